// Round 10
// baseline (1309.692 us; speedup 1.0000x reference)
//
#include <hip/hip_runtime.h>

#define NUM_TASKS 8
#define NUM_TABLES 16
#define HASH 1000000
#define BATCH 8192
#define NNZ (BATCH * 20)
#define OFF_ROW (BATCH + 1)
#define NPASS 16
#define RANGE (HASH / NPASS)        // 62500
#define SUB 12500                   // floats per LDS sub-stage (50 KB)
#define NSUB 5                      // RANGE / SUB
#define CHUNK 640
#define NCHUNK (NNZ / CHUNK)        // 256
#define SORT_STRIDE (NNZ + 512)

// ws layout (bytes). hist/bb/cbag live INSIDE the partial region but are dead
// before gather (the only writer of partial) runs — safe aliasing.
#define WS_PART  0ull                                   // [16p][16t][8task][8192b] f32 = 64 MB
#define WS_HIST  0ull                                   // [16t][16k][256c] u32 = 256 KB
#define WS_BB    262144ull                              // [16t][16k] u32
#define WS_CNTB  263168ull                              // [16t][16k] u32
#define WS_CBAG  (1ull << 20)                           // [16t][16k][8192b] u32 = 8 MB
#define PART_BYTES ((size_t)NPASS * NUM_TABLES * BATCH * NUM_TASKS * 4)   // 67,108,864
#define WS_RP    PART_BYTES                             // [16t][16k][8193] u32 = 8.39 MB
#define RP_BYTES ((size_t)NUM_TABLES * NPASS * (BATCH + 1) * 4)
#define WS_SORT  (WS_RP + RP_BYTES)                     // [16t][SORT_STRIDE] u32 = 10.5 MB
#define WS_NEED  (WS_SORT + (size_t)NUM_TABLES * SORT_STRIDE * 4)         // ~86 MB

// ---------- 1) per-chunk histogram + zero cbag ----------
__global__ void hist_kernel(const int* __restrict__ indices, unsigned* __restrict__ hist,
                            uint4* __restrict__ cbag_v)   // 524288 uint4 = 8 MB
{
    int zt = blockIdx.x * blockDim.x + threadIdx.x;
    uint4 z = make_uint4(0u, 0u, 0u, 0u);
    cbag_v[zt * 2]     = z;
    cbag_v[zt * 2 + 1] = z;

    __shared__ int h[4][NPASS];
    int w = threadIdx.x >> 6, lane = threadIdx.x & 63;
    int g = blockIdx.x * 4 + w;
    int t = g >> 8, chunk = g & 255;
    if (lane < NPASS) h[w][lane] = 0;
    __syncthreads();
    const int* ip = indices + (size_t)t * NNZ + chunk * CHUNK;
    for (int r = 0; r < CHUNK / 64; ++r) {
        int k = ip[r * 64 + lane] / RANGE;
        atomicAdd(&h[w][k], 1);
    }
    __syncthreads();
    if (lane < NPASS) hist[((size_t)t * NPASS + lane) * NCHUNK + chunk] = (unsigned)h[w][lane];
}

// ---------- 2) scan: per-(t,k) exclusive chunk scan + 32-aligned bucket bases ----------
__global__ void scan_kernel(unsigned* __restrict__ hist, unsigned* __restrict__ bb, unsigned* __restrict__ cnt)
{
    int t = blockIdx.x, tid = threadIdx.x;
    __shared__ unsigned tot[NPASS];
    if (tid < NPASS) {
        unsigned run = 0;
        unsigned* hp = hist + ((size_t)t * NPASS + tid) * NCHUNK;
        for (int c = 0; c < NCHUNK; ++c) { unsigned v = hp[c]; hp[c] = run; run += v; }
        tot[tid] = run;
        cnt[t * NPASS + tid] = run;
    }
    __syncthreads();
    if (tid == 0) {
        unsigned base = 0;
        for (int k = 0; k < NPASS; ++k) { bb[t * NPASS + k] = base; base += (tot[k] + 31u) & ~31u; }
    }
}

// ---------- 3) stable scatter + per-(t,k,bag) counts ----------
__global__ void scatter_kernel(const int* __restrict__ indices, const int* __restrict__ offsets,
                               const unsigned* __restrict__ hist, const unsigned* __restrict__ bb,
                               unsigned* __restrict__ sorted, unsigned* __restrict__ cbag)
{
    int w = threadIdx.x >> 6, lane = threadIdx.x & 63;
    int g = blockIdx.x * 4 + w;
    int t = g >> 8, chunk = g & 255;
    unsigned cur = 0;
    if (lane < NPASS)
        cur = bb[t * NPASS + lane] + hist[((size_t)t * NPASS + lane) * NCHUNK + chunk];
    unsigned long long mlt = (1ull << lane) - 1ull;
    const int* off = offsets + t * OFF_ROW;
    const int* ip  = indices + (size_t)t * NNZ;
    unsigned* sp   = sorted + (size_t)t * SORT_STRIDE;

    for (int r = 0; r < CHUNK / 64; ++r) {
        int i = chunk * CHUNK + r * 64 + lane;
        int raw = ip[i];
        int k   = raw / RANGE;
        int hlo = raw - k * RANGE;
        int lo = 0, hi = BATCH;                 // bag: largest lo with off[lo] <= i
#pragma unroll
        for (int s = 0; s < 13; ++s) {
            int mid = (lo + hi) >> 1;
            if (off[mid] <= i) lo = mid; else hi = mid;
        }
        unsigned pos = 0;
#pragma unroll
        for (int kk = 0; kk < NPASS; ++kk) {
            unsigned long long m = __ballot(k == kk);
            unsigned bc = (unsigned)__shfl((int)cur, kk, 64);
            if (k == kk) pos = bc + (unsigned)__popcll(m & mlt);
            if (lane == kk) cur += (unsigned)__popcll(m);
        }
        sp[pos] = (unsigned)hlo;
        atomicAdd(&cbag[((size_t)t * NPASS + k) * BATCH + lo], 1u);
    }
}

// ---------- 4) rowptr: per-(t,k) exclusive scan of per-bag counts ----------
__global__ void rowptr_kernel(const unsigned* __restrict__ cbag, const unsigned* __restrict__ bb,
                              unsigned* __restrict__ rowptr)
{
    int tk = blockIdx.x;                      // t*16 + k
    const unsigned* c = cbag + (size_t)tk * BATCH;
    unsigned* rp = rowptr + (size_t)tk * (BATCH + 1);
    __shared__ unsigned tsum[256];
    int tid = threadIdx.x;
    unsigned loc[32];
    unsigned s = 0;
#pragma unroll
    for (int e = 0; e < 32; ++e) { loc[e] = c[tid * 32 + e]; s += loc[e]; }
    tsum[tid] = s;
    __syncthreads();
    if (tid == 0) {
        unsigned run = 0;
        for (int j = 0; j < 256; ++j) { unsigned v = tsum[j]; tsum[j] = run; run += v; }
    }
    __syncthreads();
    unsigned run = bb[tk] + tsum[tid];
#pragma unroll
    for (int e = 0; e < 32; ++e) { rp[tid * 32 + e] = run; run += loc[e]; }
    if (tid == 255) rp[BATCH] = run;
}

// ---------- 5) LDS-staged gather: block = (pass, table, task). ----------
// Stream the 250 KB W window through LDS in 5 x 50 KB coalesced sub-stages
// (W read from HBM exactly once, sequentially, 512 MB total); resolve the
// bucket's entries as LDS gathers. Thread owns 16 bags, acc in registers,
// atomic-free coalesced partial write. 3 blocks/CU (150 KB LDS) overlap
// each other's stage/process phases.
__global__ __launch_bounds__(512)
void gather_kernel(const float* __restrict__ W, const unsigned* __restrict__ sorted,
                   const unsigned* __restrict__ rowptr, float* __restrict__ partial)
{
    __shared__ float lds[SUB];                // 50 KB

    const int bid  = blockIdx.x;              // 2048 = 16p * 16t * 8task
    const int task = bid & 7;
    const int t    = (bid >> 3) & 15;
    const int p    = bid >> 7;
    const int tid  = threadIdx.x;

    const float*    Wt = W + ((size_t)task * NUM_TABLES + t) * HASH + (size_t)p * RANGE;
    const unsigned* sp = sorted + (size_t)t * SORT_STRIDE;
    const unsigned* rp = rowptr + (size_t)(t * NPASS + p) * (BATCH + 1);

    float acc[16];
#pragma unroll
    for (int j = 0; j < 16; ++j) acc[j] = 0.0f;

    const int b0 = tid * 16;                  // this thread's 16 bags
    for (int s = 0; s < NSUB; ++s) {
        const int lo = s * SUB;
        __syncthreads();                      // previous sub-stage fully consumed
        // ---- stage 50 KB, coalesced float4 ----
        const float4* wv = (const float4*)(Wt + lo);
        float4*       lv = (float4*)lds;
        for (int i = tid; i < SUB / 4; i += 512) lv[i] = wv[i];
        __syncthreads();
        // ---- process: scan own bags, gather in-range entries from LDS ----
        unsigned u = rp[b0];
#pragma unroll 1
        for (int j = 0; j < 16; ++j) {
            unsigned e = rp[b0 + j + 1];
            for (; u < e; ++u) {
                int h = (int)sp[u] - lo;
                if ((unsigned)h < (unsigned)SUB) acc[j] += lds[h];
            }
        }
    }

    // partial[p][t][task][b]: thread writes 16 contiguous floats (64 B)
    float* pp = partial + (((size_t)(p * NUM_TABLES + t) * NUM_TASKS) + task) * BATCH + b0;
#pragma unroll
    for (int j = 0; j < 16; ++j) pp[j] = acc[j];
}

// ---------- 6) reduce 16 passes (coalesced on new partial layout) ----------
__global__ void reduce_kernel(const float* __restrict__ partial, float* __restrict__ out)
{
    int tid  = blockIdx.x * blockDim.x + threadIdx.x;   // 65536 threads
    int task = tid >> 13;                               // 0..7
    int b    = tid & (BATCH - 1);

    float s[NUM_TABLES];
#pragma unroll
    for (int t = 0; t < NUM_TABLES; ++t) s[t] = 0.0f;

    for (int p = 0; p < NPASS; ++p) {
#pragma unroll
        for (int t = 0; t < NUM_TABLES; ++t) {
            s[t] += partial[(((size_t)(p * NUM_TABLES + t) * NUM_TASKS) + task) * BATCH + b];
        }
    }

    float4* o = (float4*)(out + ((size_t)task * BATCH + b) * NUM_TABLES);
    o[0] = make_float4(s[0],  s[1],  s[2],  s[3]);
    o[1] = make_float4(s[4],  s[5],  s[6],  s[7]);
    o[2] = make_float4(s[8],  s[9],  s[10], s[11]);
    o[3] = make_float4(s[12], s[13], s[14], s[15]);
}

// ---------- fallback (round-3 kernel) if ws is too small ----------
__global__ void pool_fallback_kernel(const float* __restrict__ W, const int* __restrict__ offsets,
                                     const int* __restrict__ indices, float* __restrict__ out)
{
    const int block = blockIdx.x;
    const int t        = block >> 11;
    const int bag_base = (block & 2047) << 2;
    const int wave     = threadIdx.x >> 6;
    const int b        = bag_base + wave;
    const int lane     = threadIdx.x & 63;
    const int task     = lane & 7;
    const int split    = lane >> 3;
    const int start = offsets[t * OFF_ROW + b];
    const int end   = offsets[t * OFF_ROW + b + 1];
    const int*   idxp   = indices + (size_t)t * NNZ;
    const float* Wslice = W + ((size_t)task * NUM_TABLES + t) * (size_t)HASH;
    float acc = 0.0f;
    for (int i = start + split; i < end; i += 8) acc += Wslice[idxp[i]];
    acc += __shfl_xor(acc, 8); acc += __shfl_xor(acc, 16); acc += __shfl_xor(acc, 32);
    if (split == 0) out[((size_t)task * BATCH + b) * NUM_TABLES + t] = acc;
}

extern "C" void kernel_launch(void* const* d_in, const int* in_sizes, int n_in,
                              void* d_out, int out_size, void* d_ws, size_t ws_size,
                              hipStream_t stream) {
    const float* W       = (const float*)d_in[0];
    const int*   offsets = (const int*)d_in[1];
    const int*   indices = (const int*)d_in[2];
    float*       out     = (float*)d_out;

    if (ws_size < WS_NEED) {
        pool_fallback_kernel<<<NUM_TABLES * 2048, 256, 0, stream>>>(W, offsets, indices, out);
        return;
    }

    unsigned* hist    = (unsigned*)((char*)d_ws + WS_HIST);
    unsigned* bb      = (unsigned*)((char*)d_ws + WS_BB);
    unsigned* cntb    = (unsigned*)((char*)d_ws + WS_CNTB);
    unsigned* cbag    = (unsigned*)((char*)d_ws + WS_CBAG);
    unsigned* rowptr  = (unsigned*)((char*)d_ws + WS_RP);
    unsigned* sorted  = (unsigned*)((char*)d_ws + WS_SORT);
    float*    partial = (float*)((char*)d_ws + WS_PART);

    hist_kernel<<<(NUM_TABLES * NCHUNK) / 4, 256, 0, stream>>>(indices, hist, (uint4*)cbag);
    scan_kernel<<<NUM_TABLES, 64, 0, stream>>>(hist, bb, cntb);
    scatter_kernel<<<(NUM_TABLES * NCHUNK) / 4, 256, 0, stream>>>(indices, offsets, hist, bb, sorted, cbag);
    rowptr_kernel<<<NUM_TABLES * NPASS, 256, 0, stream>>>(cbag, bb, rowptr);
    gather_kernel<<<NPASS * NUM_TABLES * NUM_TASKS, 512, 0, stream>>>(W, sorted, rowptr, partial);
    reduce_kernel<<<(NUM_TASKS * BATCH) / 256, 256, 0, stream>>>(partial, out);
}

// Round 11
// 370.205 us; speedup vs baseline: 3.5377x; 3.5377x over previous
//
#include <hip/hip_runtime.h>

#define NUM_TASKS 8
#define NUM_TABLES 16
#define HASH 1000000
#define BATCH 8192
#define NNZ (BATCH * 20)
#define OFF_ROW (BATCH + 1)
#define NPASS 16
#define RANGE (HASH / NPASS)        // 62500 floats; RANGE/4 = 15625 float4
#define CHUNK 640
#define NCHUNK (NNZ / CHUNK)        // 256
#define SORT_STRIDE (NNZ + 512)
#define WIN_V4 (NUM_TASKS * (RANGE / 4))   // 125000 float4 per (p,t) window
#define SLICE 489                   // ceil(125000 / 256) float4 per staging block

// ws layout (bytes). hist/bb/cbag live INSIDE the partial region but are dead
// before gather (the only writer of partial) runs — safe aliasing.
#define WS_PART  0ull                                   // [16p][16t][8192b][8task] f32 = 64 MB
#define WS_HIST  0ull                                   // [16t][16k][256c] u32 = 256 KB
#define WS_BB    262144ull                              // [16t][16k] u32
#define WS_CNTB  263168ull                              // [16t][16k] u32
#define WS_CBAG  (1ull << 20)                           // [16t][16k][8192b] u32 = 8 MB
#define PART_BYTES ((size_t)NPASS * NUM_TABLES * BATCH * NUM_TASKS * 4)   // 67,108,864
#define WS_RP    PART_BYTES                             // [16t][16k][8193] u32 = 8.39 MB
#define RP_BYTES ((size_t)NUM_TABLES * NPASS * (BATCH + 1) * 4)
#define WS_SORT  (WS_RP + RP_BYTES)                     // [16t][SORT_STRIDE] u32 = 10.5 MB
#define WS_NEED  (WS_SORT + (size_t)NUM_TABLES * SORT_STRIDE * 4)         // ~86 MB

// ---------- 1) per-chunk histogram + zero cbag ----------
__global__ void hist_kernel(const int* __restrict__ indices, unsigned* __restrict__ hist,
                            uint4* __restrict__ cbag_v)   // 524288 uint4 = 8 MB
{
    int zt = blockIdx.x * blockDim.x + threadIdx.x;
    uint4 z = make_uint4(0u, 0u, 0u, 0u);
    cbag_v[zt * 2]     = z;
    cbag_v[zt * 2 + 1] = z;

    __shared__ int h[4][NPASS];
    int w = threadIdx.x >> 6, lane = threadIdx.x & 63;
    int g = blockIdx.x * 4 + w;
    int t = g >> 8, chunk = g & 255;
    if (lane < NPASS) h[w][lane] = 0;
    __syncthreads();
    const int* ip = indices + (size_t)t * NNZ + chunk * CHUNK;
    for (int r = 0; r < CHUNK / 64; ++r) {
        int k = ip[r * 64 + lane] / RANGE;
        atomicAdd(&h[w][k], 1);
    }
    __syncthreads();
    if (lane < NPASS) hist[((size_t)t * NPASS + lane) * NCHUNK + chunk] = (unsigned)h[w][lane];
}

// ---------- 2) scan: per-(t,k) exclusive chunk scan + 32-aligned bucket bases ----------
__global__ void scan_kernel(unsigned* __restrict__ hist, unsigned* __restrict__ bb, unsigned* __restrict__ cnt)
{
    int t = blockIdx.x, tid = threadIdx.x;
    __shared__ unsigned tot[NPASS];
    if (tid < NPASS) {
        unsigned run = 0;
        unsigned* hp = hist + ((size_t)t * NPASS + tid) * NCHUNK;
        for (int c = 0; c < NCHUNK; ++c) { unsigned v = hp[c]; hp[c] = run; run += v; }
        tot[tid] = run;
        cnt[t * NPASS + tid] = run;
    }
    __syncthreads();
    if (tid == 0) {
        unsigned base = 0;
        for (int k = 0; k < NPASS; ++k) { bb[t * NPASS + k] = base; base += (tot[k] + 31u) & ~31u; }
    }
}

// ---------- 3) stable scatter + per-(t,k,bag) counts ----------
__global__ void scatter_kernel(const int* __restrict__ indices, const int* __restrict__ offsets,
                               const unsigned* __restrict__ hist, const unsigned* __restrict__ bb,
                               unsigned* __restrict__ sorted, unsigned* __restrict__ cbag)
{
    int w = threadIdx.x >> 6, lane = threadIdx.x & 63;
    int g = blockIdx.x * 4 + w;
    int t = g >> 8, chunk = g & 255;
    unsigned cur = 0;
    if (lane < NPASS)
        cur = bb[t * NPASS + lane] + hist[((size_t)t * NPASS + lane) * NCHUNK + chunk];
    unsigned long long mlt = (1ull << lane) - 1ull;
    const int* off = offsets + t * OFF_ROW;
    const int* ip  = indices + (size_t)t * NNZ;
    unsigned* sp   = sorted + (size_t)t * SORT_STRIDE;

    for (int r = 0; r < CHUNK / 64; ++r) {
        int i = chunk * CHUNK + r * 64 + lane;
        int raw = ip[i];
        int k   = raw / RANGE;
        int hlo = raw - k * RANGE;
        int lo = 0, hi = BATCH;                 // bag: largest lo with off[lo] <= i
#pragma unroll
        for (int s = 0; s < 13; ++s) {
            int mid = (lo + hi) >> 1;
            if (off[mid] <= i) lo = mid; else hi = mid;
        }
        unsigned pos = 0;
#pragma unroll
        for (int kk = 0; kk < NPASS; ++kk) {
            unsigned long long m = __ballot(k == kk);
            unsigned bc = (unsigned)__shfl((int)cur, kk, 64);
            if (k == kk) pos = bc + (unsigned)__popcll(m & mlt);
            if (lane == kk) cur += (unsigned)__popcll(m);
        }
        sp[pos] = (unsigned)hlo;
        atomicAdd(&cbag[((size_t)t * NPASS + k) * BATCH + lo], 1u);
    }
}

// ---------- 4) rowptr: per-(t,k) exclusive scan of per-bag counts ----------
__global__ void rowptr_kernel(const unsigned* __restrict__ cbag, const unsigned* __restrict__ bb,
                              unsigned* __restrict__ rowptr)
{
    int tk = blockIdx.x;                      // t*16 + k
    const unsigned* c = cbag + (size_t)tk * BATCH;
    unsigned* rp = rowptr + (size_t)tk * (BATCH + 1);
    __shared__ unsigned tsum[256];
    int tid = threadIdx.x;
    unsigned loc[32];
    unsigned s = 0;
#pragma unroll
    for (int e = 0; e < 32; ++e) { loc[e] = c[tid * 32 + e]; s += loc[e]; }
    tsum[tid] = s;
    __syncthreads();
    if (tid == 0) {
        unsigned run = 0;
        for (int j = 0; j < 256; ++j) { unsigned v = tsum[j]; tsum[j] = run; run += v; }
    }
    __syncthreads();
    unsigned run = bb[tk] + tsum[tid];
#pragma unroll
    for (int e = 0; e < 32; ++e) { rp[tid * 32 + e] = run; run += loc[e]; }
    if (tid == 255) rp[BATCH] = run;
}

// ---------- 5) gather with in-block L2 window streaming ----------
// Round-6 shape: 65536 tiny blocks, group = (p, table-half) of 2048 blocks,
// dispatch-order serialized. Capacity fact: 256 thr / low VGPR -> 8 blocks/CU
// -> EXACTLY 2048 resident blocks = one group co-resident. Each block first
// streams its 1/256 slice of the group's 16 MB W window into L2 (coalesced
// float4, asm-sunk, vmcnt(0)); sequential HBM at ~6 TB/s replaces the random
// 64B first-touch (~2.1 TB/s) that bound round 6. Gathers then hit L2
// (2 MB/XCD window; +next group = 4 MB = L2 capacity).
__global__ void gather_kernel(const float* __restrict__ W, const unsigned* __restrict__ sorted,
                              const unsigned* __restrict__ rowptr, float* __restrict__ partial)
{
    int bid = blockIdx.x;
    int x   = bid & 7;                 // xcd slot
    int q   = bid >> 3;
    int blk = q & 255;  q >>= 8;
    int tp  = q & 1;    int p = q >> 1;  // p slowest: groups serialized by dispatch
    int t   = x + (tp << 3);             // table pinned to XCD slot
    int tid = threadIdx.x;

    // ---- stage slice blk of the (p,t) window: 8 tasks x 250 KB ----
    {
        int f0 = blk * SLICE;
        int f1 = min(WIN_V4, f0 + SLICE);
        for (int f = f0 + tid; f < f1; f += 256) {
            int tau = f / (RANGE / 4);            // const divisor -> magic mul
            int r   = f - tau * (RANGE / 4);
            const float4* src = (const float4*)(W + ((size_t)tau * NUM_TABLES + t) * HASH
                                                  + (size_t)p * RANGE);
            float4 v = src[r];
            asm volatile("" :: "v"(v.x), "v"(v.y), "v"(v.z), "v"(v.w));
        }
    }

    // ---- gather (round-6 proven shape) ----
    int task = tid & 7;
    int b = (blk << 5) + (tid >> 3);

    const unsigned* rp = rowptr + (size_t)(t * NPASS + p) * (BATCH + 1);
    unsigned s0 = rp[b], s1 = rp[b + 1];

    asm volatile("s_waitcnt vmcnt(0)");   // stage (and rp) complete before random reads

    const unsigned* sp = sorted + (size_t)t * SORT_STRIDE;
    const float* Wt = W + ((size_t)task * NUM_TABLES + t) * HASH + (size_t)p * RANGE;

    float acc = 0.0f;
    for (unsigned u = s0; u < s1; ++u) acc += Wt[sp[u]];

    partial[(((size_t)p * NUM_TABLES + t) * BATCH + b) * 8 + task] = acc;
}

// ---------- 6) reduce 16 passes ----------
__global__ void reduce_kernel(const float* __restrict__ partial, float* __restrict__ out)
{
    int tid  = blockIdx.x * blockDim.x + threadIdx.x;   // 65536 threads
    int task = tid & 7;
    int b    = tid >> 3;

    float s[NUM_TABLES];
#pragma unroll
    for (int t = 0; t < NUM_TABLES; ++t) s[t] = 0.0f;

    for (int p = 0; p < NPASS; ++p) {
#pragma unroll
        for (int t = 0; t < NUM_TABLES; ++t) {
            s[t] += partial[((((size_t)p * NUM_TABLES + t) * BATCH + b) << 3) + task];
        }
    }

    float4* o = (float4*)(out + ((size_t)task * BATCH + b) * NUM_TABLES);
    o[0] = make_float4(s[0],  s[1],  s[2],  s[3]);
    o[1] = make_float4(s[4],  s[5],  s[6],  s[7]);
    o[2] = make_float4(s[8],  s[9],  s[10], s[11]);
    o[3] = make_float4(s[12], s[13], s[14], s[15]);
}

// ---------- fallback (round-3 kernel) if ws is too small ----------
__global__ void pool_fallback_kernel(const float* __restrict__ W, const int* __restrict__ offsets,
                                     const int* __restrict__ indices, float* __restrict__ out)
{
    const int block = blockIdx.x;
    const int t        = block >> 11;
    const int bag_base = (block & 2047) << 2;
    const int wave     = threadIdx.x >> 6;
    const int b        = bag_base + wave;
    const int lane     = threadIdx.x & 63;
    const int task     = lane & 7;
    const int split    = lane >> 3;
    const int start = offsets[t * OFF_ROW + b];
    const int end   = offsets[t * OFF_ROW + b + 1];
    const int*   idxp   = indices + (size_t)t * NNZ;
    const float* Wslice = W + ((size_t)task * NUM_TABLES + t) * (size_t)HASH;
    float acc = 0.0f;
    for (int i = start + split; i < end; i += 8) acc += Wslice[idxp[i]];
    acc += __shfl_xor(acc, 8); acc += __shfl_xor(acc, 16); acc += __shfl_xor(acc, 32);
    if (split == 0) out[((size_t)task * BATCH + b) * NUM_TABLES + t] = acc;
}

extern "C" void kernel_launch(void* const* d_in, const int* in_sizes, int n_in,
                              void* d_out, int out_size, void* d_ws, size_t ws_size,
                              hipStream_t stream) {
    const float* W       = (const float*)d_in[0];
    const int*   offsets = (const int*)d_in[1];
    const int*   indices = (const int*)d_in[2];
    float*       out     = (float*)d_out;

    if (ws_size < WS_NEED) {
        pool_fallback_kernel<<<NUM_TABLES * 2048, 256, 0, stream>>>(W, offsets, indices, out);
        return;
    }

    unsigned* hist    = (unsigned*)((char*)d_ws + WS_HIST);
    unsigned* bb      = (unsigned*)((char*)d_ws + WS_BB);
    unsigned* cntb    = (unsigned*)((char*)d_ws + WS_CNTB);
    unsigned* cbag    = (unsigned*)((char*)d_ws + WS_CBAG);
    unsigned* rowptr  = (unsigned*)((char*)d_ws + WS_RP);
    unsigned* sorted  = (unsigned*)((char*)d_ws + WS_SORT);
    float*    partial = (float*)((char*)d_ws + WS_PART);

    hist_kernel<<<(NUM_TABLES * NCHUNK) / 4, 256, 0, stream>>>(indices, hist, (uint4*)cbag);
    scan_kernel<<<NUM_TABLES, 64, 0, stream>>>(hist, bb, cntb);
    scatter_kernel<<<(NUM_TABLES * NCHUNK) / 4, 256, 0, stream>>>(indices, offsets, hist, bb, sorted, cbag);
    rowptr_kernel<<<NUM_TABLES * NPASS, 256, 0, stream>>>(cbag, bb, rowptr);
    gather_kernel<<<NPASS * 2 * 256 * 8, 256, 0, stream>>>(W, sorted, rowptr, partial);
    reduce_kernel<<<(NUM_TASKS * BATCH) / 256, 256, 0, stream>>>(partial, out);
}

// Round 12
// 226.021 us; speedup vs baseline: 5.7946x; 1.6379x over previous
//
#include <hip/hip_runtime.h>

#define NUM_TASKS 8
#define NUM_TABLES 16
#define HASH 1000000
#define BATCH 8192
#define NNZ (BATCH * 20)
#define OFF_ROW (BATCH + 1)
#define NPASS 16
#define RANGE (HASH / NPASS)        // 62500 (fits 16 bits)
#define CHUNK 640
#define NCHUNK (NNZ / CHUNK)        // 256
#define SORT_STRIDE (NNZ + 512)
#define FS_CAP 11264                // finesort LDS capacity (mean 10240, +10 sigma)

// ws layout (bytes). No aliasing: control arrays live AFTER sorted.
#define WS_PART  0ull                                   // [16p][16t][8task][8192b] f32 = 64 MB
#define PART_BYTES ((size_t)NPASS * NUM_TABLES * BATCH * NUM_TASKS * 4)   // 67,108,864
#define WS_SORT  PART_BYTES                             // [16t][SORT_STRIDE] u32 = 10.5 MB
#define SORT_BYTES ((size_t)NUM_TABLES * SORT_STRIDE * 4)
#define WS_HIST  (WS_SORT + SORT_BYTES)                 // [16t][16k][256c] u32 = 256 KB
#define WS_BB    (WS_HIST + 262144ull)                  // [16t][16k] u32
#define WS_CNTB  (WS_BB + 1024ull)                      // [16t][16k] u32
#define WS_NEED  (WS_CNTB + 1024ull)                    // ~75 MB

// ---------- 1) per-chunk histogram ----------
__global__ void hist_kernel(const int* __restrict__ indices, unsigned* __restrict__ hist)
{
    __shared__ int h[4][NPASS];
    int w = threadIdx.x >> 6, lane = threadIdx.x & 63;
    int g = blockIdx.x * 4 + w;
    int t = g >> 8, chunk = g & 255;
    if (lane < NPASS) h[w][lane] = 0;
    __syncthreads();
    const int* ip = indices + (size_t)t * NNZ + chunk * CHUNK;
    for (int r = 0; r < CHUNK / 64; ++r) {
        int k = ip[r * 64 + lane] / RANGE;
        atomicAdd(&h[w][k], 1);
    }
    __syncthreads();
    if (lane < NPASS) hist[((size_t)t * NPASS + lane) * NCHUNK + chunk] = (unsigned)h[w][lane];
}

// ---------- 2) scan: per-(t,k) exclusive chunk scan + 32-aligned bucket bases ----------
__global__ void scan_kernel(unsigned* __restrict__ hist, unsigned* __restrict__ bb, unsigned* __restrict__ cnt)
{
    int t = blockIdx.x, tid = threadIdx.x;
    __shared__ unsigned tot[NPASS];
    if (tid < NPASS) {
        unsigned run = 0;
        unsigned* hp = hist + ((size_t)t * NPASS + tid) * NCHUNK;
        for (int c = 0; c < NCHUNK; ++c) { unsigned v = hp[c]; hp[c] = run; run += v; }
        tot[tid] = run;
        cnt[t * NPASS + tid] = run;
    }
    __syncthreads();
    if (tid == 0) {
        unsigned base = 0;
        for (int k = 0; k < NPASS; ++k) { bb[t * NPASS + k] = base; base += (tot[k] + 31u) & ~31u; }
    }
}

// ---------- 3) stable scatter: pack (h_lo<<16 | bag) into 16 h-range buckets ----------
__global__ void scatter_kernel(const int* __restrict__ indices, const int* __restrict__ offsets,
                               const unsigned* __restrict__ hist, const unsigned* __restrict__ bb,
                               unsigned* __restrict__ sorted)
{
    int w = threadIdx.x >> 6, lane = threadIdx.x & 63;
    int g = blockIdx.x * 4 + w;
    int t = g >> 8, chunk = g & 255;
    unsigned cur = 0;
    if (lane < NPASS)
        cur = bb[t * NPASS + lane] + hist[((size_t)t * NPASS + lane) * NCHUNK + chunk];
    unsigned long long mlt = (1ull << lane) - 1ull;
    const int* off = offsets + t * OFF_ROW;
    const int* ip  = indices + (size_t)t * NNZ;
    unsigned* sp   = sorted + (size_t)t * SORT_STRIDE;

    for (int r = 0; r < CHUNK / 64; ++r) {
        int i = chunk * CHUNK + r * 64 + lane;
        int raw = ip[i];
        int k   = raw / RANGE;
        int hlo = raw - k * RANGE;
        int lo = 0, hi = BATCH;                 // bag: largest lo with off[lo] <= i
#pragma unroll
        for (int s = 0; s < 13; ++s) {
            int mid = (lo + hi) >> 1;
            if (off[mid] <= i) lo = mid; else hi = mid;
        }
        unsigned pos = 0;
#pragma unroll
        for (int kk = 0; kk < NPASS; ++kk) {
            unsigned long long m = __ballot(k == kk);
            unsigned bc = (unsigned)__shfl((int)cur, kk, 64);
            if (k == kk) pos = bc + (unsigned)__popcll(m & mlt);
            if (lane == kk) cur += (unsigned)__popcll(m);
        }
        sp[pos] = ((unsigned)hlo << 16) | (unsigned)lo;
    }
}

// ---------- 4) fine sort: per (t,k) bucket, 256-way counting sort on h_lo>>8 ----------
// After this, entries within a bucket are h-ascending at 244-slot (~1KB W)
// granularity -> the gather's W walk becomes a monotone sweep (HBM row hits).
__global__ __launch_bounds__(256)
void finesort_kernel(unsigned* __restrict__ sorted, const unsigned* __restrict__ bb,
                     const unsigned* __restrict__ cnt)
{
    __shared__ unsigned ebuf[FS_CAP];         // 44 KB
    __shared__ unsigned hcnt[256];
    __shared__ unsigned hstart[256];
    int tk = blockIdx.x;                      // t*16 + k
    int t = tk >> 4;
    unsigned n = cnt[tk];
    unsigned* sp = sorted + (size_t)t * SORT_STRIDE + bb[tk];
    int tid = threadIdx.x;
    if (n > FS_CAP) return;                   // leave bag-ordered (still correct)

    hcnt[tid] = 0;
    __syncthreads();
    for (unsigned i = tid; i < n; i += 256) {
        unsigned e = sp[i];
        ebuf[i] = e;
        atomicAdd(&hcnt[e >> 24], 1u);        // e>>24 = h_lo>>8 (h_lo < 62500 < 2^16)
    }
    __syncthreads();
    if (tid == 0) {
        unsigned run = 0;
        for (int j = 0; j < 256; ++j) { hstart[j] = run; run += hcnt[j]; }
    }
    __syncthreads();
    hcnt[tid] = 0;                            // reuse as cursor
    __syncthreads();
    for (unsigned i = tid; i < n; i += 256) {
        unsigned e = ebuf[i];
        unsigned sb = e >> 24;
        unsigned pos = hstart[sb] + atomicAdd(&hcnt[sb], 1u);
        sp[pos] = e;                          // in-place safe: all entries buffered
    }
}

// ---------- 5) h-major gather: block=(p,t,task), LDS bag accumulator ----------
// Entries are h-ascending -> W reads sweep the 250KB window monotonically
// (64 consecutive entries span ~1.5KB, ~2.6 loads/line, row-hit friendly).
// atomicAdd into 32KB LDS accum (ds_add_f32), one coalesced partial write.
__global__ __launch_bounds__(256)
void gather_kernel(const float* __restrict__ W, const unsigned* __restrict__ sorted,
                   const unsigned* __restrict__ bb, const unsigned* __restrict__ cnt,
                   float* __restrict__ partial)
{
    __shared__ float accum[BATCH];            // 32 KB
    const int bid  = blockIdx.x;              // 2048 = 16p*16t*8task
    const int task = bid & 7;
    const int t    = (bid >> 3) & 15;
    const int p    = bid >> 7;
    const int tid  = threadIdx.x;

    float4* av = (float4*)accum;
    float4 z4 = make_float4(0.f, 0.f, 0.f, 0.f);
#pragma unroll
    for (int i = 0; i < BATCH / 4 / 256; ++i) av[i * 256 + tid] = z4;
    __syncthreads();

    const unsigned n = cnt[t * NPASS + p];
    const unsigned* ep = sorted + (size_t)t * SORT_STRIDE + bb[t * NPASS + p];
    const float* Wt = W + ((size_t)task * NUM_TABLES + t) * HASH + (size_t)p * RANGE;

    for (unsigned i = tid; i < n; i += 256) {
        unsigned e = ep[i];
        atomicAdd(&accum[e & 0xFFFFu], Wt[e >> 16]);
    }
    __syncthreads();

    float4* pp = (float4*)(partial + (((size_t)(p * NUM_TABLES + t) * NUM_TASKS) + task) * BATCH);
#pragma unroll
    for (int i = 0; i < BATCH / 4 / 256; ++i) pp[i * 256 + tid] = av[i * 256 + tid];
}

// ---------- 6) reduce 16 passes (coalesced) ----------
__global__ void reduce_kernel(const float* __restrict__ partial, float* __restrict__ out)
{
    int tid  = blockIdx.x * blockDim.x + threadIdx.x;   // 65536 threads
    int task = tid >> 13;                               // 0..7
    int b    = tid & (BATCH - 1);

    float s[NUM_TABLES];
#pragma unroll
    for (int t = 0; t < NUM_TABLES; ++t) s[t] = 0.0f;

    for (int p = 0; p < NPASS; ++p) {
#pragma unroll
        for (int t = 0; t < NUM_TABLES; ++t) {
            s[t] += partial[(((size_t)(p * NUM_TABLES + t) * NUM_TASKS) + task) * BATCH + b];
        }
    }

    float4* o = (float4*)(out + ((size_t)task * BATCH + b) * NUM_TABLES);
    o[0] = make_float4(s[0],  s[1],  s[2],  s[3]);
    o[1] = make_float4(s[4],  s[5],  s[6],  s[7]);
    o[2] = make_float4(s[8],  s[9],  s[10], s[11]);
    o[3] = make_float4(s[12], s[13], s[14], s[15]);
}

// ---------- fallback (round-3 kernel) if ws is too small ----------
__global__ void pool_fallback_kernel(const float* __restrict__ W, const int* __restrict__ offsets,
                                     const int* __restrict__ indices, float* __restrict__ out)
{
    const int block = blockIdx.x;
    const int t        = block >> 11;
    const int bag_base = (block & 2047) << 2;
    const int wave     = threadIdx.x >> 6;
    const int b        = bag_base + wave;
    const int lane     = threadIdx.x & 63;
    const int task     = lane & 7;
    const int split    = lane >> 3;
    const int start = offsets[t * OFF_ROW + b];
    const int end   = offsets[t * OFF_ROW + b + 1];
    const int*   idxp   = indices + (size_t)t * NNZ;
    const float* Wslice = W + ((size_t)task * NUM_TABLES + t) * (size_t)HASH;
    float acc = 0.0f;
    for (int i = start + split; i < end; i += 8) acc += Wslice[idxp[i]];
    acc += __shfl_xor(acc, 8); acc += __shfl_xor(acc, 16); acc += __shfl_xor(acc, 32);
    if (split == 0) out[((size_t)task * BATCH + b) * NUM_TABLES + t] = acc;
}

extern "C" void kernel_launch(void* const* d_in, const int* in_sizes, int n_in,
                              void* d_out, int out_size, void* d_ws, size_t ws_size,
                              hipStream_t stream) {
    const float* W       = (const float*)d_in[0];
    const int*   offsets = (const int*)d_in[1];
    const int*   indices = (const int*)d_in[2];
    float*       out     = (float*)d_out;

    if (ws_size < WS_NEED) {
        pool_fallback_kernel<<<NUM_TABLES * 2048, 256, 0, stream>>>(W, offsets, indices, out);
        return;
    }

    float*    partial = (float*)((char*)d_ws + WS_PART);
    unsigned* sorted  = (unsigned*)((char*)d_ws + WS_SORT);
    unsigned* hist    = (unsigned*)((char*)d_ws + WS_HIST);
    unsigned* bb      = (unsigned*)((char*)d_ws + WS_BB);
    unsigned* cntb    = (unsigned*)((char*)d_ws + WS_CNTB);

    hist_kernel<<<(NUM_TABLES * NCHUNK) / 4, 256, 0, stream>>>(indices, hist);
    scan_kernel<<<NUM_TABLES, 64, 0, stream>>>(hist, bb, cntb);
    scatter_kernel<<<(NUM_TABLES * NCHUNK) / 4, 256, 0, stream>>>(indices, offsets, hist, bb, sorted);
    finesort_kernel<<<NUM_TABLES * NPASS, 256, 0, stream>>>(sorted, bb, cntb);
    gather_kernel<<<NPASS * NUM_TABLES * NUM_TASKS, 256, 0, stream>>>(W, sorted, bb, cntb, partial);
    reduce_kernel<<<(NUM_TASKS * BATCH) / 256, 256, 0, stream>>>(partial, out);
}

// Round 13
// 207.501 us; speedup vs baseline: 6.3117x; 1.0893x over previous
//
#include <hip/hip_runtime.h>

#define NUM_TASKS 8
#define NUM_TABLES 16
#define HASH 1000000
#define BATCH 8192
#define NNZ (BATCH * 20)
#define OFF_ROW (BATCH + 1)
#define NPASS 16
#define RANGE (HASH / NPASS)        // 62500 (fits 16 bits)
#define CHUNK 640
#define NCHUNK (NNZ / CHUNK)        // 256
#define SORT_STRIDE (NNZ + 512)
#define FS_CAP 11264                // finesort LDS capacity (mean 10240, +10 sigma)
#define NPG 2                       // pass-groups in gather (8 passes each)

// ws layout (bytes). No aliasing.
#define WS_PART  0ull                                   // [2pg][16t][8task][8192b] f32 = 8 MB
#define PART_BYTES ((size_t)NPG * NUM_TABLES * NUM_TASKS * BATCH * 4)     // 8,388,608
#define WS_SORT  PART_BYTES                             // [16t][SORT_STRIDE] u32 = 10.5 MB
#define SORT_BYTES ((size_t)NUM_TABLES * SORT_STRIDE * 4)
#define WS_HIST  (WS_SORT + SORT_BYTES)                 // [16t][16k][256c] u32 = 256 KB
#define WS_BB    (WS_HIST + 262144ull)                  // [16t][16k] u32
#define WS_CNTB  (WS_BB + 1024ull)                      // [16t][16k] u32
#define WS_NEED  (WS_CNTB + 1024ull)                    // ~19 MB

// ---------- 1) per-chunk histogram ----------
__global__ void hist_kernel(const int* __restrict__ indices, unsigned* __restrict__ hist)
{
    __shared__ int h[4][NPASS];
    int w = threadIdx.x >> 6, lane = threadIdx.x & 63;
    int g = blockIdx.x * 4 + w;
    int t = g >> 8, chunk = g & 255;
    if (lane < NPASS) h[w][lane] = 0;
    __syncthreads();
    const int* ip = indices + (size_t)t * NNZ + chunk * CHUNK;
    for (int r = 0; r < CHUNK / 64; ++r) {
        int k = ip[r * 64 + lane] / RANGE;
        atomicAdd(&h[w][k], 1);
    }
    __syncthreads();
    if (lane < NPASS) hist[((size_t)t * NPASS + lane) * NCHUNK + chunk] = (unsigned)h[w][lane];
}

// ---------- 2) scan: per-(t,k) exclusive chunk scan + 32-aligned bucket bases ----------
__global__ void scan_kernel(unsigned* __restrict__ hist, unsigned* __restrict__ bb, unsigned* __restrict__ cnt)
{
    int t = blockIdx.x, tid = threadIdx.x;
    __shared__ unsigned tot[NPASS];
    if (tid < NPASS) {
        unsigned run = 0;
        unsigned* hp = hist + ((size_t)t * NPASS + tid) * NCHUNK;
        for (int c = 0; c < NCHUNK; ++c) { unsigned v = hp[c]; hp[c] = run; run += v; }
        tot[tid] = run;
        cnt[t * NPASS + tid] = run;
    }
    __syncthreads();
    if (tid == 0) {
        unsigned base = 0;
        for (int k = 0; k < NPASS; ++k) { bb[t * NPASS + k] = base; base += (tot[k] + 31u) & ~31u; }
    }
}

// ---------- 3) stable scatter: pack (h_lo<<16 | bag) into 16 h-range buckets ----------
__global__ void scatter_kernel(const int* __restrict__ indices, const int* __restrict__ offsets,
                               const unsigned* __restrict__ hist, const unsigned* __restrict__ bb,
                               unsigned* __restrict__ sorted)
{
    int w = threadIdx.x >> 6, lane = threadIdx.x & 63;
    int g = blockIdx.x * 4 + w;
    int t = g >> 8, chunk = g & 255;
    unsigned cur = 0;
    if (lane < NPASS)
        cur = bb[t * NPASS + lane] + hist[((size_t)t * NPASS + lane) * NCHUNK + chunk];
    unsigned long long mlt = (1ull << lane) - 1ull;
    const int* off = offsets + t * OFF_ROW;
    const int* ip  = indices + (size_t)t * NNZ;
    unsigned* sp   = sorted + (size_t)t * SORT_STRIDE;

    for (int r = 0; r < CHUNK / 64; ++r) {
        int i = chunk * CHUNK + r * 64 + lane;
        int raw = ip[i];
        int k   = raw / RANGE;
        int hlo = raw - k * RANGE;
        int lo = 0, hi = BATCH;                 // bag: largest lo with off[lo] <= i
#pragma unroll
        for (int s = 0; s < 13; ++s) {
            int mid = (lo + hi) >> 1;
            if (off[mid] <= i) lo = mid; else hi = mid;
        }
        unsigned pos = 0;
#pragma unroll
        for (int kk = 0; kk < NPASS; ++kk) {
            unsigned long long m = __ballot(k == kk);
            unsigned bc = (unsigned)__shfl((int)cur, kk, 64);
            if (k == kk) pos = bc + (unsigned)__popcll(m & mlt);
            if (lane == kk) cur += (unsigned)__popcll(m);
        }
        sp[pos] = ((unsigned)hlo << 16) | (unsigned)lo;
    }
}

// ---------- 4) fine sort: per (t,k) bucket, 256-way counting sort on h_lo>>8 ----------
__global__ __launch_bounds__(256)
void finesort_kernel(unsigned* __restrict__ sorted, const unsigned* __restrict__ bb,
                     const unsigned* __restrict__ cnt)
{
    __shared__ unsigned ebuf[FS_CAP];         // 44 KB
    __shared__ unsigned hcnt[256];
    __shared__ unsigned hstart[256];
    int tk = blockIdx.x;                      // t*16 + k
    int t = tk >> 4;
    unsigned n = cnt[tk];
    unsigned* sp = sorted + (size_t)t * SORT_STRIDE + bb[tk];
    int tid = threadIdx.x;
    if (n > FS_CAP) return;                   // leave bag-ordered (still correct)

    hcnt[tid] = 0;
    __syncthreads();
    for (unsigned i = tid; i < n; i += 256) {
        unsigned e = sp[i];
        ebuf[i] = e;
        atomicAdd(&hcnt[e >> 24], 1u);        // e>>24 = h_lo>>8
    }
    __syncthreads();
    if (tid == 0) {
        unsigned run = 0;
        for (int j = 0; j < 256; ++j) { hstart[j] = run; run += hcnt[j]; }
    }
    __syncthreads();
    hcnt[tid] = 0;                            // reuse as cursor
    __syncthreads();
    for (unsigned i = tid; i < n; i += 256) {
        unsigned e = ebuf[i];
        unsigned sb = e >> 24;
        unsigned pos = hstart[sb] + atomicAdd(&hcnt[sb], 1u);
        sp[pos] = e;
    }
}

// ---------- 5) h-major gather, 8 passes per block ----------
// block = (pg, t, task): walks buckets p = pg*8 .. pg*8+7 back-to-back, each
// h-ascending -> one monotone sweep of a contiguous 2 MB W region. Grid = 256
// blocks = 1/CU: concurrent HBM streams drop 2048 -> 256 (~2/channel), so
// row-buffer hits dominate (round 12's 2048 interleaved streams were the
// residual inefficiency). All 8 buckets accumulate into ONE LDS accum[8192];
// partial shrinks to [2][16][8][8192] = 8 MB, reduce becomes a 2-way sum.
__global__ __launch_bounds__(1024)
void gather_kernel(const float* __restrict__ W, const unsigned* __restrict__ sorted,
                   const unsigned* __restrict__ bb, const unsigned* __restrict__ cnt,
                   float* __restrict__ partial)
{
    __shared__ float accum[BATCH];            // 32 KB
    const int bid  = blockIdx.x;              // 256 = 2pg * 16t * 8task
    const int task = bid & 7;
    const int t    = (bid >> 3) & 15;
    const int pg   = bid >> 7;
    const int tid  = threadIdx.x;

    float4* av = (float4*)accum;
    float4 z4 = make_float4(0.f, 0.f, 0.f, 0.f);
    av[tid]        = z4;
    av[tid + 1024] = z4;
    __syncthreads();

    const float* Wbase = W + ((size_t)task * NUM_TABLES + t) * HASH;

#pragma unroll 1
    for (int j = 0; j < NPASS / NPG; ++j) {
        const int p = pg * (NPASS / NPG) + j;
        const unsigned n = cnt[t * NPASS + p];
        const unsigned* ep = sorted + (size_t)t * SORT_STRIDE + bb[t * NPASS + p];
        const float* Wt = Wbase + (size_t)p * RANGE;
        for (unsigned i = tid; i < n; i += 1024) {
            unsigned e = ep[i];
            atomicAdd(&accum[e & 0xFFFFu], Wt[e >> 16]);
        }
    }
    __syncthreads();

    float4* pp = (float4*)(partial + (((size_t)(pg * NUM_TABLES + t) * NUM_TASKS) + task) * BATCH);
    pp[tid]        = av[tid];
    pp[tid + 1024] = av[tid + 1024];
}

// ---------- 6) reduce 2 pass-groups (coalesced) ----------
__global__ void reduce_kernel(const float* __restrict__ partial, float* __restrict__ out)
{
    int tid  = blockIdx.x * blockDim.x + threadIdx.x;   // 65536 threads
    int task = tid >> 13;                               // 0..7
    int b    = tid & (BATCH - 1);

    float s[NUM_TABLES];
#pragma unroll
    for (int t = 0; t < NUM_TABLES; ++t) {
        s[t] = partial[(((size_t)(0 * NUM_TABLES + t) * NUM_TASKS) + task) * BATCH + b]
             + partial[(((size_t)(1 * NUM_TABLES + t) * NUM_TASKS) + task) * BATCH + b];
    }

    float4* o = (float4*)(out + ((size_t)task * BATCH + b) * NUM_TABLES);
    o[0] = make_float4(s[0],  s[1],  s[2],  s[3]);
    o[1] = make_float4(s[4],  s[5],  s[6],  s[7]);
    o[2] = make_float4(s[8],  s[9],  s[10], s[11]);
    o[3] = make_float4(s[12], s[13], s[14], s[15]);
}

// ---------- fallback (round-3 kernel) if ws is too small ----------
__global__ void pool_fallback_kernel(const float* __restrict__ W, const int* __restrict__ offsets,
                                     const int* __restrict__ indices, float* __restrict__ out)
{
    const int block = blockIdx.x;
    const int t        = block >> 11;
    const int bag_base = (block & 2047) << 2;
    const int wave     = threadIdx.x >> 6;
    const int b        = bag_base + wave;
    const int lane     = threadIdx.x & 63;
    const int task     = lane & 7;
    const int split    = lane >> 3;
    const int start = offsets[t * OFF_ROW + b];
    const int end   = offsets[t * OFF_ROW + b + 1];
    const int*   idxp   = indices + (size_t)t * NNZ;
    const float* Wslice = W + ((size_t)task * NUM_TABLES + t) * (size_t)HASH;
    float acc = 0.0f;
    for (int i = start + split; i < end; i += 8) acc += Wslice[idxp[i]];
    acc += __shfl_xor(acc, 8); acc += __shfl_xor(acc, 16); acc += __shfl_xor(acc, 32);
    if (split == 0) out[((size_t)task * BATCH + b) * NUM_TABLES + t] = acc;
}

extern "C" void kernel_launch(void* const* d_in, const int* in_sizes, int n_in,
                              void* d_out, int out_size, void* d_ws, size_t ws_size,
                              hipStream_t stream) {
    const float* W       = (const float*)d_in[0];
    const int*   offsets = (const int*)d_in[1];
    const int*   indices = (const int*)d_in[2];
    float*       out     = (float*)d_out;

    if (ws_size < WS_NEED) {
        pool_fallback_kernel<<<NUM_TABLES * 2048, 256, 0, stream>>>(W, offsets, indices, out);
        return;
    }

    float*    partial = (float*)((char*)d_ws + WS_PART);
    unsigned* sorted  = (unsigned*)((char*)d_ws + WS_SORT);
    unsigned* hist    = (unsigned*)((char*)d_ws + WS_HIST);
    unsigned* bb      = (unsigned*)((char*)d_ws + WS_BB);
    unsigned* cntb    = (unsigned*)((char*)d_ws + WS_CNTB);

    hist_kernel<<<(NUM_TABLES * NCHUNK) / 4, 256, 0, stream>>>(indices, hist);
    scan_kernel<<<NUM_TABLES, 64, 0, stream>>>(hist, bb, cntb);
    scatter_kernel<<<(NUM_TABLES * NCHUNK) / 4, 256, 0, stream>>>(indices, offsets, hist, bb, sorted);
    finesort_kernel<<<NUM_TABLES * NPASS, 256, 0, stream>>>(sorted, bb, cntb);
    gather_kernel<<<NPG * NUM_TABLES * NUM_TASKS, 1024, 0, stream>>>(W, sorted, bb, cntb, partial);
    reduce_kernel<<<(NUM_TASKS * BATCH) / 256, 256, 0, stream>>>(partial, out);
}

// Round 14
// 194.138 us; speedup vs baseline: 6.7462x; 1.0688x over previous
//
#include <hip/hip_runtime.h>

#define NUM_TASKS 8
#define NUM_TABLES 16
#define HASH 1000000
#define BATCH 8192
#define NNZ (BATCH * 20)
#define OFF_ROW (BATCH + 1)
#define NPASS 16
#define RANGE (HASH / NPASS)        // 62500 (fits 16 bits)
#define CHUNK 640
#define NCHUNK (NNZ / CHUNK)        // 256
#define SORT_STRIDE (NNZ + 512)
#define FS_CAP 11264                // finesort LDS capacity (mean 10240, +10 sigma)
#define NPG 4                       // pass-groups in gather (4 passes each)

// ws layout (bytes). No aliasing.
#define WS_PART  0ull                                   // [4pg][16t][8task][8192b] f32 = 16 MB
#define PART_BYTES ((size_t)NPG * NUM_TABLES * NUM_TASKS * BATCH * 4)     // 16,777,216
#define WS_SORT  PART_BYTES                             // [16t][SORT_STRIDE] u32 = 10.5 MB
#define SORT_BYTES ((size_t)NUM_TABLES * SORT_STRIDE * 4)
#define WS_HIST  (WS_SORT + SORT_BYTES)                 // [16t][16k][256c] u32 = 256 KB
#define WS_BB    (WS_HIST + 262144ull)                  // [16t][16k] u32
#define WS_CNTB  (WS_BB + 1024ull)                      // [16t][16k] u32
#define WS_NEED  (WS_CNTB + 1024ull)                    // ~28 MB

// ---------- 1) per-chunk histogram ----------
__global__ void hist_kernel(const int* __restrict__ indices, unsigned* __restrict__ hist)
{
    __shared__ int h[4][NPASS];
    int w = threadIdx.x >> 6, lane = threadIdx.x & 63;
    int g = blockIdx.x * 4 + w;
    int t = g >> 8, chunk = g & 255;
    if (lane < NPASS) h[w][lane] = 0;
    __syncthreads();
    const int* ip = indices + (size_t)t * NNZ + chunk * CHUNK;
    for (int r = 0; r < CHUNK / 64; ++r) {
        int k = ip[r * 64 + lane] / RANGE;
        atomicAdd(&h[w][k], 1);
    }
    __syncthreads();
    if (lane < NPASS) hist[((size_t)t * NPASS + lane) * NCHUNK + chunk] = (unsigned)h[w][lane];
}

// ---------- 2) scan: per-(t,k) exclusive chunk scan + 32-aligned bucket bases ----------
__global__ void scan_kernel(unsigned* __restrict__ hist, unsigned* __restrict__ bb, unsigned* __restrict__ cnt)
{
    int t = blockIdx.x, tid = threadIdx.x;
    __shared__ unsigned tot[NPASS];
    if (tid < NPASS) {
        unsigned run = 0;
        unsigned* hp = hist + ((size_t)t * NPASS + tid) * NCHUNK;
        for (int c = 0; c < NCHUNK; ++c) { unsigned v = hp[c]; hp[c] = run; run += v; }
        tot[tid] = run;
        cnt[t * NPASS + tid] = run;
    }
    __syncthreads();
    if (tid == 0) {
        unsigned base = 0;
        for (int k = 0; k < NPASS; ++k) { bb[t * NPASS + k] = base; base += (tot[k] + 31u) & ~31u; }
    }
}

// ---------- 3) stable scatter: pack (h_lo<<16 | bag) into 16 h-range buckets ----------
__global__ void scatter_kernel(const int* __restrict__ indices, const int* __restrict__ offsets,
                               const unsigned* __restrict__ hist, const unsigned* __restrict__ bb,
                               unsigned* __restrict__ sorted)
{
    int w = threadIdx.x >> 6, lane = threadIdx.x & 63;
    int g = blockIdx.x * 4 + w;
    int t = g >> 8, chunk = g & 255;
    unsigned cur = 0;
    if (lane < NPASS)
        cur = bb[t * NPASS + lane] + hist[((size_t)t * NPASS + lane) * NCHUNK + chunk];
    unsigned long long mlt = (1ull << lane) - 1ull;
    const int* off = offsets + t * OFF_ROW;
    const int* ip  = indices + (size_t)t * NNZ;
    unsigned* sp   = sorted + (size_t)t * SORT_STRIDE;

    for (int r = 0; r < CHUNK / 64; ++r) {
        int i = chunk * CHUNK + r * 64 + lane;
        int raw = ip[i];
        int k   = raw / RANGE;
        int hlo = raw - k * RANGE;
        int lo = 0, hi = BATCH;                 // bag: largest lo with off[lo] <= i
#pragma unroll
        for (int s = 0; s < 13; ++s) {
            int mid = (lo + hi) >> 1;
            if (off[mid] <= i) lo = mid; else hi = mid;
        }
        unsigned pos = 0;
#pragma unroll
        for (int kk = 0; kk < NPASS; ++kk) {
            unsigned long long m = __ballot(k == kk);
            unsigned bc = (unsigned)__shfl((int)cur, kk, 64);
            if (k == kk) pos = bc + (unsigned)__popcll(m & mlt);
            if (lane == kk) cur += (unsigned)__popcll(m);
        }
        sp[pos] = ((unsigned)hlo << 16) | (unsigned)lo;
    }
}

// ---------- 4) fine sort: per (t,k) bucket, 256-way counting sort on h_lo>>8 ----------
__global__ __launch_bounds__(256)
void finesort_kernel(unsigned* __restrict__ sorted, const unsigned* __restrict__ bb,
                     const unsigned* __restrict__ cnt)
{
    __shared__ unsigned ebuf[FS_CAP];         // 44 KB
    __shared__ unsigned hcnt[256];
    __shared__ unsigned hstart[256];
    int tk = blockIdx.x;                      // t*16 + k
    int t = tk >> 4;
    unsigned n = cnt[tk];
    unsigned* sp = sorted + (size_t)t * SORT_STRIDE + bb[tk];
    int tid = threadIdx.x;
    if (n > FS_CAP) return;                   // leave bag-ordered (still correct)

    hcnt[tid] = 0;
    __syncthreads();
    for (unsigned i = tid; i < n; i += 256) {
        unsigned e = sp[i];
        ebuf[i] = e;
        atomicAdd(&hcnt[e >> 24], 1u);        // e>>24 = h_lo>>8
    }
    __syncthreads();
    if (tid == 0) {
        unsigned run = 0;
        for (int j = 0; j < 256; ++j) { hstart[j] = run; run += hcnt[j]; }
    }
    __syncthreads();
    hcnt[tid] = 0;                            // reuse as cursor
    __syncthreads();
    for (unsigned i = tid; i < n; i += 256) {
        unsigned e = ebuf[i];
        unsigned sb = e >> 24;
        unsigned pos = hstart[sb] + atomicAdd(&hcnt[sb], 1u);
        sp[pos] = e;
    }
}

// ---------- 5) h-major gather, 4 passes per block, uint2 entry loads ----------
// block = (pg, t, task): walks buckets p = pg*4 .. pg*4+3 back-to-back, each
// h-ascending -> one monotone sweep of a contiguous 1 MB W region. Grid = 512
// = 2 blocks/CU = 32 waves/CU (FULL occupancy; round 13 was at 50%) and the
// uint2 read gives 2 independent W loads per thread-iteration -> ~4x the
// outstanding HBM requests that bound round 13 at 4.1 TB/s effective.
__global__ __launch_bounds__(1024)
void gather_kernel(const float* __restrict__ W, const unsigned* __restrict__ sorted,
                   const unsigned* __restrict__ bb, const unsigned* __restrict__ cnt,
                   float* __restrict__ partial)
{
    __shared__ float accum[BATCH];            // 32 KB (2 blocks/CU -> 64 KB/CU, fits)
    const int bid  = blockIdx.x;              // 512 = 4pg * 16t * 8task
    const int task = bid & 7;
    const int t    = (bid >> 3) & 15;
    const int pg   = bid >> 7;
    const int tid  = threadIdx.x;

    float4* av = (float4*)accum;
    float4 z4 = make_float4(0.f, 0.f, 0.f, 0.f);
    av[tid]        = z4;
    av[tid + 1024] = z4;
    __syncthreads();

    const float* Wbase = W + ((size_t)task * NUM_TABLES + t) * HASH;

#pragma unroll 1
    for (int j = 0; j < NPASS / NPG; ++j) {
        const int p = pg * (NPASS / NPG) + j;
        const unsigned n = cnt[t * NPASS + p];
        const unsigned* ep = sorted + (size_t)t * SORT_STRIDE + bb[t * NPASS + p];
        const float* Wt = Wbase + (size_t)p * RANGE;
        const uint2* ep2 = (const uint2*)ep;  // buckets 32-aligned -> 8B aligned
        const unsigned npair = n >> 1;
        for (unsigned i = tid; i < npair; i += 1024) {
            uint2 e = ep2[i];
            float v0 = Wt[e.x >> 16];
            float v1 = Wt[e.y >> 16];
            atomicAdd(&accum[e.x & 0xFFFFu], v0);
            atomicAdd(&accum[e.y & 0xFFFFu], v1);
        }
        if (tid == 0 && (n & 1u)) {
            unsigned e = ep[n - 1];
            atomicAdd(&accum[e & 0xFFFFu], Wt[e >> 16]);
        }
    }
    __syncthreads();

    float4* pp = (float4*)(partial + (((size_t)(pg * NUM_TABLES + t) * NUM_TASKS) + task) * BATCH);
    pp[tid]        = av[tid];
    pp[tid + 1024] = av[tid + 1024];
}

// ---------- 6) reduce 4 pass-groups (coalesced) ----------
__global__ void reduce_kernel(const float* __restrict__ partial, float* __restrict__ out)
{
    int tid  = blockIdx.x * blockDim.x + threadIdx.x;   // 65536 threads
    int task = tid >> 13;                               // 0..7
    int b    = tid & (BATCH - 1);

    float s[NUM_TABLES];
#pragma unroll
    for (int t = 0; t < NUM_TABLES; ++t) {
        float a = 0.f;
#pragma unroll
        for (int pg = 0; pg < NPG; ++pg)
            a += partial[(((size_t)(pg * NUM_TABLES + t) * NUM_TASKS) + task) * BATCH + b];
        s[t] = a;
    }

    float4* o = (float4*)(out + ((size_t)task * BATCH + b) * NUM_TABLES);
    o[0] = make_float4(s[0],  s[1],  s[2],  s[3]);
    o[1] = make_float4(s[4],  s[5],  s[6],  s[7]);
    o[2] = make_float4(s[8],  s[9],  s[10], s[11]);
    o[3] = make_float4(s[12], s[13], s[14], s[15]);
}

// ---------- fallback (round-3 kernel) if ws is too small ----------
__global__ void pool_fallback_kernel(const float* __restrict__ W, const int* __restrict__ offsets,
                                     const int* __restrict__ indices, float* __restrict__ out)
{
    const int block = blockIdx.x;
    const int t        = block >> 11;
    const int bag_base = (block & 2047) << 2;
    const int wave     = threadIdx.x >> 6;
    const int b        = bag_base + wave;
    const int lane     = threadIdx.x & 63;
    const int task     = lane & 7;
    const int split    = lane >> 3;
    const int start = offsets[t * OFF_ROW + b];
    const int end   = offsets[t * OFF_ROW + b + 1];
    const int*   idxp   = indices + (size_t)t * NNZ;
    const float* Wslice = W + ((size_t)task * NUM_TABLES + t) * (size_t)HASH;
    float acc = 0.0f;
    for (int i = start + split; i < end; i += 8) acc += Wslice[idxp[i]];
    acc += __shfl_xor(acc, 8); acc += __shfl_xor(acc, 16); acc += __shfl_xor(acc, 32);
    if (split == 0) out[((size_t)task * BATCH + b) * NUM_TABLES + t] = acc;
}

extern "C" void kernel_launch(void* const* d_in, const int* in_sizes, int n_in,
                              void* d_out, int out_size, void* d_ws, size_t ws_size,
                              hipStream_t stream) {
    const float* W       = (const float*)d_in[0];
    const int*   offsets = (const int*)d_in[1];
    const int*   indices = (const int*)d_in[2];
    float*       out     = (float*)d_out;

    if (ws_size < WS_NEED) {
        pool_fallback_kernel<<<NUM_TABLES * 2048, 256, 0, stream>>>(W, offsets, indices, out);
        return;
    }

    float*    partial = (float*)((char*)d_ws + WS_PART);
    unsigned* sorted  = (unsigned*)((char*)d_ws + WS_SORT);
    unsigned* hist    = (unsigned*)((char*)d_ws + WS_HIST);
    unsigned* bb      = (unsigned*)((char*)d_ws + WS_BB);
    unsigned* cntb    = (unsigned*)((char*)d_ws + WS_CNTB);

    hist_kernel<<<(NUM_TABLES * NCHUNK) / 4, 256, 0, stream>>>(indices, hist);
    scan_kernel<<<NUM_TABLES, 64, 0, stream>>>(hist, bb, cntb);
    scatter_kernel<<<(NUM_TABLES * NCHUNK) / 4, 256, 0, stream>>>(indices, offsets, hist, bb, sorted);
    finesort_kernel<<<NUM_TABLES * NPASS, 256, 0, stream>>>(sorted, bb, cntb);
    gather_kernel<<<NPG * NUM_TABLES * NUM_TASKS, 1024, 0, stream>>>(W, sorted, bb, cntb, partial);
    reduce_kernel<<<(NUM_TASKS * BATCH) / 256, 256, 0, stream>>>(partial, out);
}